// Round 1
// baseline (799.760 us; speedup 1.0000x reference)
//
#include <hip/hip_runtime.h>
#include <stdint.h>

// Problem constants (Attention_48945447306134):
//   x:(4,2048,2048) f32, freqs_cos/sin:(2048,64) f32,
//   wq:(2048,2048), wk/wv:(2048,512), wo:(2048,2048) f32.  Output f32 (4,2048,2048).
// Strategy: everything in bf16 MFMA (16x16x32) with fp32 accum.
//   GEMM1: QKV = xb @ [wq|wk|wv]  (M=8192,N=3072,K=2048), bf16 out
//   RoPE on Q,K cols in place; V pre-transposed to Vt[b][hk][d][s]
//   Flash attention: 128-row Q tile, 16 K-tiles of 128, online softmax
//   GEMM2: out = attn @ woT (fp32 out to d_out)

typedef unsigned short u16;
typedef __bf16 bf16x8 __attribute__((ext_vector_type(8)));
typedef float  f32x4  __attribute__((ext_vector_type(4)));

#define GLOAD16(gp, lp)                                                        \
  __builtin_amdgcn_global_load_lds(                                            \
      (const __attribute__((address_space(1))) void*)(gp),                     \
      (__attribute__((address_space(3))) void*)(lp), 16, 0, 0)

__device__ __forceinline__ u16 f2b(float f) {  // RNE f32->bf16
  union { float f; uint32_t u; } v; v.f = f;
  uint32_t r = v.u + 0x7FFFu + ((v.u >> 16) & 1u);
  return (u16)(r >> 16);
}
__device__ __forceinline__ float b2f(u16 h) {
  union { uint32_t u; float f; } v; v.u = ((uint32_t)h) << 16;
  return v.f;
}

// ---------------- cast x -> bf16 (16M elems, 4/thread) ----------------
__global__ __launch_bounds__(256) void cast_x_kernel(const float4* __restrict__ in,
                                                     ushort4* __restrict__ out) {
  int i = blockIdx.x * 256 + threadIdx.x;
  float4 v = in[i];
  ushort4 o;
  o.x = f2b(v.x); o.y = f2b(v.y); o.z = f2b(v.z); o.w = f2b(v.w);
  out[i] = o;
}

// ------------- cast + transpose weight: W (KxN f32) -> WT (NxK bf16) -------------
__global__ __launch_bounds__(256) void wtrans_kernel(const float* __restrict__ W,
                                                     u16* __restrict__ WT,
                                                     int K, int N) {
  __shared__ float t[32][33];
  int n0 = blockIdx.x * 32, k0 = blockIdx.y * 32;
  int tx = threadIdx.x, ty = threadIdx.y;  // 32 x 8
  for (int r = 0; r < 4; r++)
    t[ty + r * 8][tx] = W[(size_t)(k0 + ty + r * 8) * N + n0 + tx];
  __syncthreads();
  for (int r = 0; r < 4; r++)
    WT[(size_t)(n0 + ty + r * 8) * K + k0 + tx] = f2b(t[tx][ty + r * 8]);
}

// ---------------- GEMM: C(MxN) = A(MxK) * BT(NxK)^T, bf16 in, m97 structure ----------------
template <bool BF16OUT>
__global__ __launch_bounds__(256) void gemm_bt_kernel(const u16* __restrict__ A,
                                                      const u16* __restrict__ BT,
                                                      void* __restrict__ Cv,
                                                      int K, int N) {
  __shared__ u16 As[128 * 32];
  __shared__ u16 Bs[128 * 32];
  const int tid = threadIdx.x;
  const int wave = tid >> 6, lane = tid & 63;
  const int quad = lane >> 4, l16 = lane & 15;
  const int wm = (wave >> 1) * 64, wn = (wave & 1) * 64;
  const size_t m0 = (size_t)blockIdx.y * 128, n0 = (size_t)blockIdx.x * 128;

  f32x4 acc[4][4] = {};
  const int srow = lane >> 2;        // row within 16-row wave slice (64B rows)
  const int scol = (lane & 3) * 8;   // elem offset within row
  const u16* Ag = A + (m0 + wave * 16 + srow) * (size_t)K + scol;
  const u16* Bg = BT + (n0 + wave * 16 + srow) * (size_t)K + scol;

  for (int k0 = 0; k0 < K; k0 += 32) {
    for (int rd = 0; rd < 2; rd++) {
      GLOAD16(Ag + (size_t)rd * 64 * K + k0, &As[(rd * 64 + wave * 16) * 32]);
      GLOAD16(Bg + (size_t)rd * 64 * K + k0, &Bs[(rd * 64 + wave * 16) * 32]);
    }
    __syncthreads();
    bf16x8 af[4], bf[4];
    for (int i = 0; i < 4; i++)
      af[i] = *(const bf16x8*)&As[(wm + i * 16 + l16) * 32 + quad * 8];
    for (int i = 0; i < 4; i++)
      bf[i] = *(const bf16x8*)&Bs[(wn + i * 16 + l16) * 32 + quad * 8];
    for (int mi = 0; mi < 4; mi++)
      for (int ni = 0; ni < 4; ni++)
        acc[mi][ni] = __builtin_amdgcn_mfma_f32_16x16x32_bf16(af[mi], bf[ni], acc[mi][ni], 0, 0, 0);
    __syncthreads();
  }
  // epilogue: C/D layout col=lane&15, row=quad*4+reg (m89-verified)
  for (int mi = 0; mi < 4; mi++)
    for (int ni = 0; ni < 4; ni++)
      for (int r = 0; r < 4; r++) {
        size_t row = m0 + wm + mi * 16 + quad * 4 + r;
        size_t col = n0 + wn + ni * 16 + l16;
        if (BF16OUT) ((u16*)Cv)[row * N + col] = f2b(acc[mi][ni][r]);
        else         ((float*)Cv)[row * N + col] = acc[mi][ni][r];
      }
}

// ---------------- RoPE in place on QKV cols [0,2560) ----------------
// head 0..15 = Q heads, head 16..19 = K heads (K starts at col 2048 = 16*128)
__global__ __launch_bounds__(256) void rope_kernel(u16* __restrict__ QKV,
                                                   const float* __restrict__ cs,
                                                   const float* __restrict__ sn) {
  int tid = blockIdx.x * 256 + threadIdx.x;  // 8192*1280 exact
  int row = tid / 1280;
  int p = tid - row * 1280;
  int s = row & 2047;
  int head = p >> 6, i = p & 63;
  u16* ptr = QKV + (size_t)row * 3072 + head * 128 + i * 2;
  unsigned int v = *(unsigned int*)ptr;
  float x0 = b2f((u16)(v & 0xffff)), x1 = b2f((u16)(v >> 16));
  float c = cs[s * 64 + i], ss = sn[s * 64 + i];
  u16 o0 = f2b(x0 * c - x1 * ss);
  u16 o1 = f2b(x0 * ss + x1 * c);
  *(unsigned int*)ptr = (unsigned int)o0 | ((unsigned int)o1 << 16);
}

// ---------------- V transpose: QKV V-cols -> Vt[(b*4+hk)*128+d][s] ----------------
__global__ __launch_bounds__(256) void vtrans_kernel(const u16* __restrict__ QKV,
                                                     u16* __restrict__ Vt) {
  __shared__ u16 t[32][33];
  int b = blockIdx.z >> 2, hk = blockIdx.z & 3;
  int s0 = blockIdx.x * 32, d0 = blockIdx.y * 32;
  int tx = threadIdx.x, ty = threadIdx.y;
  const u16* src = QKV + (size_t)(b * 2048 + s0) * 3072 + 2560 + hk * 128 + d0;
  for (int r = 0; r < 4; r++)
    t[ty + r * 8][tx] = src[(size_t)(ty + r * 8) * 3072 + tx];
  __syncthreads();
  u16* dst = Vt + ((size_t)((b * 4 + hk) * 128 + d0)) * 2048 + s0;
  for (int r = 0; r < 4; r++)
    dst[(size_t)(ty + r * 8) * 2048 + tx] = t[tx][ty + r * 8];
}

// ---------------- flash attention ----------------
// grid (qt=16, h=16, b=4), 256 threads (4 waves, 32 q-rows each).
// LDS: KP (K tile, then reused for P) + Vls (Vt tile) = exactly 64KB.
// 256B rows would put every lane-quad on the same 4 banks; XOR chunk swizzle
// (chunk ^= row&7) applied at global_load_lds stage time spreads to all 32 banks.
__global__ __launch_bounds__(256) void attn_kernel(const u16* __restrict__ QKV,
                                                   const u16* __restrict__ Vt,
                                                   u16* __restrict__ AO) {
  __shared__ u16 KP[128 * 128];
  __shared__ u16 Vls[128 * 128];
  const int tid = threadIdx.x;
  const int wave = tid >> 6, lane = tid & 63;
  const int quad = lane >> 4, l16 = lane & 15;
  const int qt = blockIdx.x, h = blockIdx.y, b = blockIdx.z;
  const int hk = h >> 2;
  const float C = 0.08838834764831845f * 1.44269504088896340f;  // scale*log2(e)

  bf16x8 qf[2][4];
  {
    const u16* Qb = QKV + (size_t)(b * 2048 + qt * 128 + wave * 32) * 3072 + h * 128;
    for (int mi = 0; mi < 2; mi++)
      for (int ki = 0; ki < 4; ki++)
        qf[mi][ki] = *(const bf16x8*)(Qb + (size_t)(mi * 16 + l16) * 3072 + ki * 32 + quad * 8);
  }
  f32x4 o[2][8] = {};
  float mrow[2][4], lrow[2][4];
  for (int mi = 0; mi < 2; mi++)
    for (int r = 0; r < 4; r++) { mrow[mi][r] = -1e30f; lrow[mi][r] = 0.f; }

  const u16* Kg0 = QKV + 2048 + hk * 128;
  const u16* Vg0 = Vt + (size_t)((b * 4 + hk) * 128) * 2048;
  const int r4 = lane >> 4;    // staging: row within 4-row group
  const int c16 = lane & 15;   // staging: 16B chunk within 256B row

  for (int kt = 0; kt < 16; kt++) {
    {  // stage K and Vt tiles (swizzled)
      const u16* Kg = Kg0 + (size_t)(b * 2048 + kt * 128) * 3072;
      const u16* Vg = Vg0 + kt * 128;
      for (int i = 0; i < 8; i++) {
        int grp = i * 4 + wave;
        int row = grp * 4 + r4;
        int ch = c16 ^ (row & 7);
        GLOAD16(Kg + (size_t)row * 3072 + ch * 8, &KP[grp * 512]);
      }
      for (int i = 0; i < 8; i++) {
        int grp = i * 4 + wave;
        int row = grp * 4 + r4;
        int ch = c16 ^ (row & 7);
        GLOAD16(Vg + (size_t)row * 2048 + ch * 8, &Vls[grp * 512]);
      }
    }
    __syncthreads();
    // S = Q K^T  (A=Q frag, B[k=d][n=key] read from K rows)
    f32x4 s[2][8];
    for (int nb = 0; nb < 8; nb++) {
      int key = nb * 16 + l16;
      bf16x8 kf[4];
      for (int ki = 0; ki < 4; ki++) {
        int pc = (ki * 4 + quad) ^ (key & 7);
        kf[ki] = *(const bf16x8*)&KP[key * 128 + pc * 8];
      }
      for (int mi = 0; mi < 2; mi++) {
        f32x4 a = {0.f, 0.f, 0.f, 0.f};
        for (int ki = 0; ki < 4; ki++)
          a = __builtin_amdgcn_mfma_f32_16x16x32_bf16(qf[mi][ki], kf[ki], a, 0, 0, 0);
        s[mi][nb] = a;
      }
    }
    // online softmax (raw-score domain, scale folded into exp2 constant)
    for (int mi = 0; mi < 2; mi++)
      for (int r = 0; r < 4; r++) {
        float mx = s[mi][0][r];
        for (int nb = 1; nb < 8; nb++) mx = fmaxf(mx, s[mi][nb][r]);
        for (int off = 1; off < 16; off <<= 1) mx = fmaxf(mx, __shfl_xor(mx, off, 64));
        float mn = fmaxf(mrow[mi][r], mx);
        float alpha = exp2f((mrow[mi][r] - mn) * C);
        mrow[mi][r] = mn;
        float rs = 0.f;
        for (int nb = 0; nb < 8; nb++) {
          float p = exp2f((s[mi][nb][r] - mn) * C);
          s[mi][nb][r] = p;
          rs += p;
        }
        for (int off = 1; off < 16; off <<= 1) rs += __shfl_xor(rs, off, 64);
        lrow[mi][r] = lrow[mi][r] * alpha + rs;
        for (int db = 0; db < 8; db++) o[mi][db][r] *= alpha;
      }
    __syncthreads();  // all waves done reading K before P overwrites it
    // write P (bf16) into KP, swizzled; each wave writes only its 32 rows
    for (int mi = 0; mi < 2; mi++) {
      int rowb = wave * 32 + mi * 16 + quad * 4;
      for (int nb = 0; nb < 8; nb++) {
        int cb = nb * 16 + l16;
        int chunk = cb >> 3, ce = cb & 7;
        for (int r = 0; r < 4; r++) {
          int row = rowb + r;
          KP[row * 128 + ((chunk ^ (row & 7)) << 3) + ce] = f2b(s[mi][nb][r]);
        }
      }
    }
    // O += P V  (each wave reads only its own P rows -> no barrier needed here)
    bf16x8 pa[2][4];
    for (int mi = 0; mi < 2; mi++)
      for (int ki = 0; ki < 4; ki++) {
        int row = wave * 32 + mi * 16 + l16;
        int pc = (ki * 4 + quad) ^ (row & 7);
        pa[mi][ki] = *(const bf16x8*)&KP[row * 128 + pc * 8];
      }
    for (int db = 0; db < 8; db++) {
      int d = db * 16 + l16;
      bf16x8 vb[4];
      for (int ki = 0; ki < 4; ki++) {
        int pc = (ki * 4 + quad) ^ (d & 7);
        vb[ki] = *(const bf16x8*)&Vls[d * 128 + pc * 8];
      }
      for (int mi = 0; mi < 2; mi++)
        for (int ki = 0; ki < 4; ki++)
          o[mi][db] = __builtin_amdgcn_mfma_f32_16x16x32_bf16(pa[mi][ki], vb[ki], o[mi][db], 0, 0, 0);
    }
    __syncthreads();  // all reads done before next iteration restages
  }
  // epilogue: O/l -> LDS (swizzled) -> coalesced global store
  for (int mi = 0; mi < 2; mi++) {
    int rowb = wave * 32 + mi * 16 + quad * 4;
    float inv[4];
    for (int r = 0; r < 4; r++) inv[r] = 1.0f / lrow[mi][r];
    for (int db = 0; db < 8; db++) {
      int cb = db * 16 + l16;
      int chunk = cb >> 3, ce = cb & 7;
      for (int r = 0; r < 4; r++) {
        int row = rowb + r;
        KP[row * 128 + ((chunk ^ (row & 7)) << 3) + ce] = f2b(o[mi][db][r] * inv[r]);
      }
    }
  }
  __syncthreads();
  u16* Ab = AO + (size_t)(b * 2048 + qt * 128) * 2048 + h * 128;
  for (int i = 0; i < 8; i++) {
    int row = i * 16 + (tid >> 4);
    int seg = tid & 15;
    int pc = seg ^ (row & 7);
    *(uint4*)(Ab + (size_t)row * 2048 + seg * 8) = *(const uint4*)&KP[row * 128 + pc * 8];
  }
}

// ---------------- launch ----------------
extern "C" void kernel_launch(void* const* d_in, const int* in_sizes, int n_in,
                              void* d_out, int out_size, void* d_ws, size_t ws_size,
                              hipStream_t stream) {
  (void)in_sizes; (void)n_in; (void)out_size; (void)ws_size;
  const float* x    = (const float*)d_in[0];
  const float* fcos = (const float*)d_in[1];
  const float* fsin = (const float*)d_in[2];
  const float* wq   = (const float*)d_in[3];
  const float* wk   = (const float*)d_in[4];
  const float* wv   = (const float*)d_in[5];
  const float* wo   = (const float*)d_in[6];

  // workspace carve (bytes): xb/attn_out union 32MB | wT 12MB | woT 8MB | QKV 48MB | Vt 8MB
  char* w = (char*)d_ws;
  u16* xb  = (u16*)w;                               // 8192x2048 bf16 (x), reused as attn_out
  u16* wT  = (u16*)(w + 33554432);                  // 3072x2048 bf16 ([wq|wk|wv]^T)
  u16* woT = (u16*)(w + 33554432 + 12582912);       // 2048x2048 bf16
  u16* QKV = (u16*)(w + 33554432 + 12582912 + 8388608);            // 8192x3072 bf16
  u16* Vt  = (u16*)(w + 33554432 + 12582912 + 8388608 + 50331648); // 16x128x2048 bf16
  u16* AO  = xb;

  cast_x_kernel<<<16384, 256, 0, stream>>>((const float4*)x, (ushort4*)xb);
  wtrans_kernel<<<dim3(64, 64), dim3(32, 8), 0, stream>>>(wq, wT, 2048, 2048);
  wtrans_kernel<<<dim3(16, 64), dim3(32, 8), 0, stream>>>(wk, wT + (size_t)2048 * 2048, 2048, 512);
  wtrans_kernel<<<dim3(16, 64), dim3(32, 8), 0, stream>>>(wv, wT + (size_t)2560 * 2048, 2048, 512);
  wtrans_kernel<<<dim3(64, 64), dim3(32, 8), 0, stream>>>(wo, woT, 2048, 2048);

  gemm_bt_kernel<true><<<dim3(24, 64), 256, 0, stream>>>(xb, wT, QKV, 2048, 3072);
  rope_kernel<<<40960, 256, 0, stream>>>(QKV, fcos, fsin);
  vtrans_kernel<<<dim3(64, 4, 16), dim3(32, 8), 0, stream>>>(QKV, Vt);
  attn_kernel<<<dim3(16, 16, 4), 256, 0, stream>>>(QKV, Vt, AO);
  gemm_bt_kernel<false><<<dim3(16, 64), 256, 0, stream>>>(AO, woT, (float*)d_out, 2048, 2048);
}

// Round 2
// 711.473 us; speedup vs baseline: 1.1241x; 1.1241x over previous
//
#include <hip/hip_runtime.h>
#include <stdint.h>

// Attention_48945447306134 on MI355X.
//   GEMM1: QKV = xb @ [wq*C|wk|wv]^T  (wq pre-scaled by softmax_scale*log2e)
//   RoPE in place; V pre-transposed to Vt[b][hk][d][s]
//   Flash attention, TRANSPOSED algebra: S^T = K Q^T, O^T = V^T P^T
//     -> softmax reduction = 2 shuffles, P/epilogue writes packed b64,
//        alpha/l indexed directly by o-lane layout.
//   GEMM2: out = attn @ woT (fp32 out)

typedef unsigned short u16;
typedef __bf16 bf16x8 __attribute__((ext_vector_type(8)));
typedef float  f32x4  __attribute__((ext_vector_type(4)));

#define GLOAD16(gp, lp)                                                        \
  __builtin_amdgcn_global_load_lds(                                            \
      (const __attribute__((address_space(1))) void*)(gp),                     \
      (__attribute__((address_space(3))) void*)(lp), 16, 0, 0)

__device__ __forceinline__ u16 f2b(float f) {  // RNE f32->bf16
  union { float f; uint32_t u; } v; v.f = f;
  uint32_t r = v.u + 0x7FFFu + ((v.u >> 16) & 1u);
  return (u16)(r >> 16);
}
__device__ __forceinline__ float b2f(u16 h) {
  union { uint32_t u; float f; } v; v.u = ((uint32_t)h) << 16;
  return v.f;
}
__device__ __forceinline__ uint2 pack4(float a, float b, float c, float d) {
  uint2 r;
  r.x = (uint32_t)f2b(a) | ((uint32_t)f2b(b) << 16);
  r.y = (uint32_t)f2b(c) | ((uint32_t)f2b(d) << 16);
  return r;
}

// ---------------- cast x -> bf16 ----------------
__global__ __launch_bounds__(256) void cast_x_kernel(const float4* __restrict__ in,
                                                     ushort4* __restrict__ out) {
  int i = blockIdx.x * 256 + threadIdx.x;
  float4 v = in[i];
  ushort4 o;
  o.x = f2b(v.x); o.y = f2b(v.y); o.z = f2b(v.z); o.w = f2b(v.w);
  out[i] = o;
}

// ------------- cast + transpose weight: W (KxN f32) -> WT (NxK bf16), * scale -------------
__global__ __launch_bounds__(256) void wtrans_kernel(const float* __restrict__ W,
                                                     u16* __restrict__ WT,
                                                     int K, int N, float scale) {
  __shared__ float t[32][33];
  int n0 = blockIdx.x * 32, k0 = blockIdx.y * 32;
  int tx = threadIdx.x, ty = threadIdx.y;  // 32 x 8
  for (int r = 0; r < 4; r++)
    t[ty + r * 8][tx] = W[(size_t)(k0 + ty + r * 8) * N + n0 + tx];
  __syncthreads();
  for (int r = 0; r < 4; r++)
    WT[(size_t)(n0 + ty + r * 8) * K + k0 + tx] = f2b(t[tx][ty + r * 8] * scale);
}

// ---------------- GEMM: C(MxN) = A(MxK) * BT(NxK)^T, m97 structure ----------------
template <bool BF16OUT>
__global__ __launch_bounds__(256) void gemm_bt_kernel(const u16* __restrict__ A,
                                                      const u16* __restrict__ BT,
                                                      void* __restrict__ Cv,
                                                      int K, int N) {
  __shared__ u16 As[128 * 32];
  __shared__ u16 Bs[128 * 32];
  const int tid = threadIdx.x;
  const int wave = tid >> 6, lane = tid & 63;
  const int quad = lane >> 4, l16 = lane & 15;
  const int wm = (wave >> 1) * 64, wn = (wave & 1) * 64;
  const size_t m0 = (size_t)blockIdx.y * 128, n0 = (size_t)blockIdx.x * 128;

  f32x4 acc[4][4] = {};
  const int srow = lane >> 2;
  const int scol = (lane & 3) * 8;
  const u16* Ag = A + (m0 + wave * 16 + srow) * (size_t)K + scol;
  const u16* Bg = BT + (n0 + wave * 16 + srow) * (size_t)K + scol;

  for (int k0 = 0; k0 < K; k0 += 32) {
    for (int rd = 0; rd < 2; rd++) {
      GLOAD16(Ag + (size_t)rd * 64 * K + k0, &As[(rd * 64 + wave * 16) * 32]);
      GLOAD16(Bg + (size_t)rd * 64 * K + k0, &Bs[(rd * 64 + wave * 16) * 32]);
    }
    __syncthreads();
    bf16x8 af[4], bf[4];
    for (int i = 0; i < 4; i++)
      af[i] = *(const bf16x8*)&As[(wm + i * 16 + l16) * 32 + quad * 8];
    for (int i = 0; i < 4; i++)
      bf[i] = *(const bf16x8*)&Bs[(wn + i * 16 + l16) * 32 + quad * 8];
    for (int mi = 0; mi < 4; mi++)
      for (int ni = 0; ni < 4; ni++)
        acc[mi][ni] = __builtin_amdgcn_mfma_f32_16x16x32_bf16(af[mi], bf[ni], acc[mi][ni], 0, 0, 0);
    __syncthreads();
  }
  for (int mi = 0; mi < 4; mi++)
    for (int ni = 0; ni < 4; ni++)
      for (int r = 0; r < 4; r++) {
        size_t row = m0 + wm + mi * 16 + quad * 4 + r;
        size_t col = n0 + wn + ni * 16 + l16;
        if (BF16OUT) ((u16*)Cv)[row * N + col] = f2b(acc[mi][ni][r]);
        else         ((float*)Cv)[row * N + col] = acc[mi][ni][r];
      }
}

// ---------------- RoPE in place on QKV cols [0,2560) ----------------
__global__ __launch_bounds__(256) void rope_kernel(u16* __restrict__ QKV,
                                                   const float* __restrict__ cs,
                                                   const float* __restrict__ sn) {
  int tid = blockIdx.x * 256 + threadIdx.x;
  int row = tid / 1280;
  int p = tid - row * 1280;
  int s = row & 2047;
  int head = p >> 6, i = p & 63;
  u16* ptr = QKV + (size_t)row * 3072 + head * 128 + i * 2;
  unsigned int v = *(unsigned int*)ptr;
  float x0 = b2f((u16)(v & 0xffff)), x1 = b2f((u16)(v >> 16));
  float c = cs[s * 64 + i], ss = sn[s * 64 + i];
  u16 o0 = f2b(x0 * c - x1 * ss);
  u16 o1 = f2b(x0 * ss + x1 * c);
  *(unsigned int*)ptr = (unsigned int)o0 | ((unsigned int)o1 << 16);
}

// ---------------- V transpose ----------------
__global__ __launch_bounds__(256) void vtrans_kernel(const u16* __restrict__ QKV,
                                                     u16* __restrict__ Vt) {
  __shared__ u16 t[32][33];
  int b = blockIdx.z >> 2, hk = blockIdx.z & 3;
  int s0 = blockIdx.x * 32, d0 = blockIdx.y * 32;
  int tx = threadIdx.x, ty = threadIdx.y;
  const u16* src = QKV + (size_t)(b * 2048 + s0) * 3072 + 2560 + hk * 128 + d0;
  for (int r = 0; r < 4; r++)
    t[ty + r * 8][tx] = src[(size_t)(ty + r * 8) * 3072 + tx];
  __syncthreads();
  u16* dst = Vt + ((size_t)((b * 4 + hk) * 128 + d0)) * 2048 + s0;
  for (int r = 0; r < 4; r++)
    dst[(size_t)(ty + r * 8) * 2048 + tx] = t[tx][ty + r * 8];
}

// ---------------- flash attention (transposed algebra) ----------------
// grid (qt=16, h=16, b=4), 256 threads = 4 waves, 32 q-rows/wave.
// S^T = K.Q^T: C-layout col(l16)=q, row(quad*4+r)=key -> per-q softmax needs
// only xor-16/xor-32 shuffles; P packed b64 into [q][key]; O^T = V^T.P^T puts
// alpha/l on the same lanes that hold O. LDS: KP(32K, K then P) + Vls(32K).
__global__ __launch_bounds__(256, 2) void attn_kernel(const u16* __restrict__ QKV,
                                                      const u16* __restrict__ Vt,
                                                      u16* __restrict__ AO) {
  __shared__ u16 KP[128 * 128];
  __shared__ u16 Vls[128 * 128];
  const int tid = threadIdx.x;
  const int wave = tid >> 6, lane = tid & 63;
  const int quad = lane >> 4, l16 = lane & 15;
  const int qt = blockIdx.x, h = blockIdx.y, b = blockIdx.z;
  const int hk = h >> 2;
  const int sw = l16 & 7;  // row-dependent swizzle key for this lane's rows

  // Q fragments (B-operand: n=q=l16, k=d) -- identical loads as before
  bf16x8 qf[2][4];
  {
    const u16* Qb = QKV + (size_t)(b * 2048 + qt * 128 + wave * 32) * 3072 + h * 128;
    for (int qb = 0; qb < 2; qb++)
      for (int ki = 0; ki < 4; ki++)
        qf[qb][ki] = *(const bf16x8*)(Qb + (size_t)(qb * 16 + l16) * 3072 + ki * 32 + quad * 8);
  }
  f32x4 o[8][2] = {};            // O^T: [db][qb], col=q(l16), row=d(quad*4+r)
  float m_[2] = {-1e30f, -1e30f}, l_[2] = {0.f, 0.f};

  const u16* Kg0 = QKV + 2048 + hk * 128;
  const u16* Vg0 = Vt + (size_t)((b * 4 + hk) * 128) * 2048;
  const int r4 = lane >> 4, c16 = lane & 15;

  for (int kt = 0; kt < 16; kt++) {
    {  // stage K and Vt tiles (chunk-swizzled at global-address time)
      const u16* Kg = Kg0 + (size_t)(b * 2048 + kt * 128) * 3072;
      const u16* Vg = Vg0 + kt * 128;
      for (int i = 0; i < 8; i++) {
        int grp = i * 4 + wave;
        int row = grp * 4 + r4;
        int ch = c16 ^ (row & 7);
        GLOAD16(Kg + (size_t)row * 3072 + ch * 8, &KP[grp * 512]);
      }
      for (int i = 0; i < 8; i++) {
        int grp = i * 4 + wave;
        int row = grp * 4 + r4;
        int ch = c16 ^ (row & 7);
        GLOAD16(Vg + (size_t)row * 2048 + ch * 8, &Vls[grp * 512]);
      }
    }
    __syncthreads();
    // S^T = K Q^T : A = K-frag (m=key), B = Q-frag (n=q)
    f32x4 s[8][2];
    for (int kb = 0; kb < 8; kb++) {
      bf16x8 kf[4];
      int a0 = (kb * 16 + l16) * 128 + ((quad ^ sw) << 3);
      for (int ki = 0; ki < 4; ki++)
        kf[ki] = *(const bf16x8*)&KP[a0 ^ (ki * 32)];
      for (int qb = 0; qb < 2; qb++) {
        f32x4 a = {0.f, 0.f, 0.f, 0.f};
        for (int ki = 0; ki < 4; ki++)
          a = __builtin_amdgcn_mfma_f32_16x16x32_bf16(kf[ki], qf[qb][ki], a, 0, 0, 0);
        s[kb][qb] = a;
      }
    }
    // online softmax per q (q = qb*16 + l16); scores pre-scaled by C*log2e
    float alpha[2];
    for (int qb = 0; qb < 2; qb++) {
      float mx = s[0][qb][0];
      for (int kb = 0; kb < 8; kb++)
        for (int r = 0; r < 4; r++) mx = fmaxf(mx, s[kb][qb][r]);
      mx = fmaxf(mx, __shfl_xor(mx, 16, 64));
      mx = fmaxf(mx, __shfl_xor(mx, 32, 64));
      float mn = fmaxf(m_[qb], mx);
      alpha[qb] = exp2f(m_[qb] - mn);
      m_[qb] = mn;
      float rs = 0.f;
      for (int kb = 0; kb < 8; kb++)
        for (int r = 0; r < 4; r++) {
          float p = exp2f(s[kb][qb][r] - mn);
          s[kb][qb][r] = p;
          rs += p;
        }
      rs += __shfl_xor(rs, 16, 64);
      rs += __shfl_xor(rs, 32, 64);
      l_[qb] = l_[qb] * alpha[qb] + rs;
    }
    for (int db = 0; db < 8; db++)
      for (int qb = 0; qb < 2; qb++) o[db][qb] *= alpha[qb];
    __syncthreads();  // all waves' K reads done before P overwrites KP
    // P -> KP as [q][key], packed b64 (4 contiguous keys per lane)
    for (int qb = 0; qb < 2; qb++) {
      int rq = wave * 32 + qb * 16 + l16;
      for (int kb = 0; kb < 8; kb++) {
        int ch = (kb * 2 + (quad >> 1)) ^ sw;
        uint2 pv = pack4(s[kb][qb][0], s[kb][qb][1], s[kb][qb][2], s[kb][qb][3]);
        *(uint2*)&KP[rq * 128 + (ch << 3) + (quad & 1) * 4] = pv;
      }
    }
    // O^T += V^T P^T : A = V-frag (m=d), B = P-frag (n=q, own rows only)
    bf16x8 pf[2][4];
    for (int qb = 0; qb < 2; qb++) {
      int a0 = (wave * 32 + qb * 16 + l16) * 128 + ((quad ^ sw) << 3);
      for (int ki = 0; ki < 4; ki++)
        pf[qb][ki] = *(const bf16x8*)&KP[a0 ^ (ki * 32)];
    }
    for (int db = 0; db < 8; db++) {
      bf16x8 vf[4];
      int a0 = (db * 16 + l16) * 128 + ((quad ^ sw) << 3);
      for (int ki = 0; ki < 4; ki++)
        vf[ki] = *(const bf16x8*)&Vls[a0 ^ (ki * 32)];
      for (int qb = 0; qb < 2; qb++)
        for (int ki = 0; ki < 4; ki++)
          o[db][qb] = __builtin_amdgcn_mfma_f32_16x16x32_bf16(vf[ki], pf[qb][ki], o[db][qb], 0, 0, 0);
    }
    __syncthreads();  // V+P reads done before next restage
  }
  // epilogue: O^T/l -> LDS [q][d] packed b64 -> coalesced global store
  float inv[2] = {1.0f / l_[0], 1.0f / l_[1]};
  for (int qb = 0; qb < 2; qb++) {
    int rq = wave * 32 + qb * 16 + l16;
    for (int db = 0; db < 8; db++) {
      int ch = (db * 2 + (quad >> 1)) ^ sw;
      uint2 pv = pack4(o[db][qb][0] * inv[qb], o[db][qb][1] * inv[qb],
                       o[db][qb][2] * inv[qb], o[db][qb][3] * inv[qb]);
      *(uint2*)&KP[rq * 128 + (ch << 3) + (quad & 1) * 4] = pv;
    }
  }
  __syncthreads();
  u16* Ab = AO + (size_t)(b * 2048 + qt * 128) * 2048 + h * 128;
  for (int i = 0; i < 8; i++) {
    int row = i * 16 + (tid >> 4);
    int seg = tid & 15;
    int pc = seg ^ (row & 7);
    *(uint4*)(Ab + (size_t)row * 2048 + seg * 8) = *(const uint4*)&KP[row * 128 + pc * 8];
  }
}

// ---------------- launch ----------------
extern "C" void kernel_launch(void* const* d_in, const int* in_sizes, int n_in,
                              void* d_out, int out_size, void* d_ws, size_t ws_size,
                              hipStream_t stream) {
  (void)in_sizes; (void)n_in; (void)out_size; (void)ws_size;
  const float* x    = (const float*)d_in[0];
  const float* fcos = (const float*)d_in[1];
  const float* fsin = (const float*)d_in[2];
  const float* wq   = (const float*)d_in[3];
  const float* wk   = (const float*)d_in[4];
  const float* wv   = (const float*)d_in[5];
  const float* wo   = (const float*)d_in[6];

  char* w = (char*)d_ws;
  u16* xb  = (u16*)w;                               // 8192x2048 bf16, reused as attn_out
  u16* wT  = (u16*)(w + 33554432);                  // 3072x2048 bf16
  u16* woT = (u16*)(w + 33554432 + 12582912);       // 2048x2048 bf16
  u16* QKV = (u16*)(w + 33554432 + 12582912 + 8388608);            // 8192x3072 bf16
  u16* Vt  = (u16*)(w + 33554432 + 12582912 + 8388608 + 50331648); // 16x128x2048 bf16
  u16* AO  = xb;

  const float C = 0.08838834764831845f * 1.44269504088896340f;  // 1/sqrt(128)*log2(e)

  cast_x_kernel<<<16384, 256, 0, stream>>>((const float4*)x, (ushort4*)xb);
  wtrans_kernel<<<dim3(64, 64), dim3(32, 8), 0, stream>>>(wq, wT, 2048, 2048, C);
  wtrans_kernel<<<dim3(16, 64), dim3(32, 8), 0, stream>>>(wk, wT + (size_t)2048 * 2048, 2048, 512, 1.0f);
  wtrans_kernel<<<dim3(16, 64), dim3(32, 8), 0, stream>>>(wv, wT + (size_t)2560 * 2048, 2048, 512, 1.0f);
  wtrans_kernel<<<dim3(64, 64), dim3(32, 8), 0, stream>>>(wo, woT, 2048, 2048, 1.0f);

  gemm_bt_kernel<true><<<dim3(24, 64), 256, 0, stream>>>(xb, wT, QKV, 2048, 3072);
  rope_kernel<<<40960, 256, 0, stream>>>(QKV, fcos, fsin);
  vtrans_kernel<<<dim3(64, 4, 16), dim3(32, 8), 0, stream>>>(QKV, Vt);
  attn_kernel<<<dim3(16, 16, 4), 256, 0, stream>>>(QKV, Vt, AO);
  gemm_bt_kernel<false><<<dim3(16, 64), 256, 0, stream>>>(AO, woT, (float*)d_out, 2048, 2048);
}